// Round 7
// baseline (204.630 us; speedup 1.0000x reference)
//
#include <hip/hip_runtime.h>

// (B, Lq, Lk, D, C, KW) = (8, 1024, 1024, 512, 512, 3)

typedef __attribute__((ext_vector_type(8))) short s8vec;    // 8 x bf16 (4 VGPRs)
typedef __attribute__((ext_vector_type(4))) float floatx4;  // MFMA accumulator

__device__ __forceinline__ unsigned short f2bf(float f) {
    union { float f; unsigned u; } v; v.f = f;
    unsigned r = (v.u + 0x7FFFu + ((v.u >> 16) & 1u)) >> 16;
    return (unsigned short)r;
}

__device__ __forceinline__ void gl2lds16(const void* g, void* l) {
    __builtin_amdgcn_global_load_lds(
        (__attribute__((address_space(1))) void*)(g),
        (__attribute__((address_space(3))) void*)(l), 16, 0, 0);
}

// ---- fused: q->bf16, k->padded bf16, zero pad, bias = q@W_bias+b_bias,
//      and W_kernel transpose -> Wt[w][c][d] bf16 ----
__global__ void cvt_all(const float* __restrict__ q, const float* __restrict__ k,
                        unsigned short* __restrict__ qbf, unsigned short* __restrict__ kp,
                        const float* __restrict__ Wb, const float* __restrict__ b_bias,
                        float* __restrict__ biasb,
                        const float* __restrict__ W, unsigned short* __restrict__ Wt) {
    int blk = blockIdx.x;
    if (blk < 4104) {
        int t = blk * 256 + threadIdx.x;
        if (t < 524288) {                       // q: 8*1024*512 / 8
            const float4* p = (const float4*)q + 2 * (size_t)t;
            float4 a = p[0], b = p[1];
            union { unsigned short s[8]; uint4 v; } o;
            o.s[0]=f2bf(a.x); o.s[1]=f2bf(a.y); o.s[2]=f2bf(a.z); o.s[3]=f2bf(a.w);
            o.s[4]=f2bf(b.x); o.s[5]=f2bf(b.y); o.s[6]=f2bf(b.z); o.s[7]=f2bf(b.w);
            ((uint4*)qbf)[t] = o.v;
        } else if (t < 1048576) {               // k -> padded kp
            int e8 = t - 524288;
            size_t e = (size_t)e8 * 8;
            int b = e8 >> 16;
            int j = (e8 >> 6) & 1023;
            int c = (e8 & 63) * 8;
            const float4* p = (const float4*)(k + e);
            float4 a = p[0], bb = p[1];
            union { unsigned short s[8]; uint4 v; } o;
            o.s[0]=f2bf(a.x); o.s[1]=f2bf(a.y); o.s[2]=f2bf(a.z); o.s[3]=f2bf(a.w);
            o.s[4]=f2bf(bb.x); o.s[5]=f2bf(bb.y); o.s[6]=f2bf(bb.z); o.s[7]=f2bf(bb.w);
            *(uint4*)(kp + ((size_t)(b * 1028 + j + 1) * 512 + c)) = o.v;
        } else if (t < 1050624) {               // zero pad rows
            int z = t - 1048576;
            int b = z >> 8, r = (z >> 6) & 3, ch = z & 63;
            int row = r ? (1024 + r) : 0;
            *(uint4*)(kp + ((size_t)(b * 1028 + row) * 512 + ch * 8)) = make_uint4(0u,0u,0u,0u);
        }
    } else if (blk < 6152) {                    // bias: one wave per row
        int row  = (blk - 4104) * 4 + (threadIdx.x >> 6);
        int lane = threadIdx.x & 63;
        const float4* qr = (const float4*)(q + (size_t)row * 512) + lane * 2;
        const float4* wb = (const float4*)Wb + lane * 2;
        float4 a0 = qr[0], a1 = qr[1], b0 = wb[0], b1 = wb[1];
        float s = a0.x*b0.x + a0.y*b0.y + a0.z*b0.z + a0.w*b0.w
                + a1.x*b1.x + a1.y*b1.y + a1.z*b1.z + a1.w*b1.w;
        #pragma unroll
        for (int off = 32; off > 0; off >>= 1) s += __shfl_down(s, off);
        if (lane == 0) biasb[row] = s + b_bias[0];
    } else {                                    // W transpose: 32x32 tile per block
        __shared__ float lds[32][33];
        int p = blk - 6152;                     // 0..767
        int cw0 = (p % 48) * 32, d0 = (p / 48) * 32;
        int tid = threadIdx.x;
        #pragma unroll
        for (int rep = 0; rep < 4; rep++) {
            int e = rep * 256 + tid, dy = e >> 5, dx = e & 31;
            lds[dy][dx] = W[(size_t)(d0 + dy) * 1536 + cw0 + dx];
        }
        __syncthreads();
        #pragma unroll
        for (int rep = 0; rep < 4; rep++) {
            int e = rep * 256 + tid, cy = e >> 5, cx = e & 31;
            int cw = cw0 + cy, c = cw / 3, w = cw % 3;
            Wt[((size_t)(w * 512 + c)) * 512 + d0 + cx] = f2bf(lds[cx][cy]);
        }
    }
}

// ---- out_init: out[b,i,:] = biasb[b,i] + bias_b (gemm_B atomically accumulates) ----
__global__ void out_init(const float* __restrict__ biasb, const float* __restrict__ bias_b,
                         float* __restrict__ out) {
    int t = blockIdx.x * 256 + threadIdx.x;     // 262144 threads, 32 per row
    int row = t >> 5;
    float v = biasb[row] + bias_b[0];
    float4 vv = make_float4(v, v, v, v);
    float4* dst = (float4*)(out + (size_t)row * 1024) + (t & 31) * 8;
    #pragma unroll
    for (int r = 0; r < 8; r++) dst[r] = vv;
}

// ---- Phase A: G[b][w][i][c] = bf16( q_bf(8192x512) @ Wt(1536x512)^T + b_kernel )
//      64m x 128n tiles, 2-wave blocks, BK=64, grid 1536, XCD swizzle ----
__global__ __launch_bounds__(128) void gemm_A(const unsigned short* __restrict__ Abf,
                                              const unsigned short* __restrict__ Bbf,
                                              const float* __restrict__ b_kernel,
                                              unsigned short* __restrict__ G) {
    __shared__ unsigned short lds_a[64 * 64];    // 8 KB
    __shared__ unsigned short lds_b[128 * 64];   // 16 KB
    int g = blockIdx.x;                 // 0..1535
    int xcd = g & 7, slot = g >> 3;     // slot 0..191
    int i_blk = xcd * 16 + (slot & 15); // 0..127
    int n_blk = slot >> 4;              // 0..11
    int i0 = i_blk * 64, n0 = n_blk * 128;
    int tid = threadIdx.x, wid = tid >> 6, lane = tid & 63;
    floatx4 acc[4][4] = {};

    for (int kk = 0; kk < 512; kk += 64) {
        #pragma unroll
        for (int s = 0; s < 12; ++s) {
            int t = s * 2 + wid;        // 0..23; 8 rows x 128B per chunk
            if (t < 8) {
                const unsigned short* ga = Abf + (size_t)(i0 + t * 8 + (lane >> 3)) * 512 + kk + (lane & 7) * 8;
                gl2lds16(ga, (char*)lds_a + t * 1024);
            } else {
                int u = t - 8;
                const unsigned short* gb = Bbf + (size_t)(n0 + u * 8 + (lane >> 3)) * 512 + kk + (lane & 7) * 8;
                gl2lds16(gb, (char*)lds_b + u * 1024);
            }
        }
        __syncthreads();
        int ra = lane & 15, q8 = (lane >> 4) * 8;
        #pragma unroll
        for (int h = 0; h < 2; ++h) {
            s8vec af[4], bf_[4];
            #pragma unroll
            for (int mi = 0; mi < 4; mi++)
                af[mi] = *(const s8vec*)(lds_a + (mi * 16 + ra) * 64 + h * 32 + q8);
            #pragma unroll
            for (int ni = 0; ni < 4; ni++)
                bf_[ni] = *(const s8vec*)(lds_b + (wid * 64 + ni * 16 + ra) * 64 + h * 32 + q8);
            #pragma unroll
            for (int mi = 0; mi < 4; mi++)
                #pragma unroll
                for (int ni = 0; ni < 4; ni++)
                    acc[mi][ni] = __builtin_amdgcn_mfma_f32_16x16x32_bf16(af[mi], bf_[ni], acc[mi][ni], 0, 0, 0);
        }
        __syncthreads();
    }

    int cl = lane & 15, qd = lane >> 4;
    #pragma unroll
    for (int mi = 0; mi < 4; mi++) {
        #pragma unroll
        for (int ni = 0; ni < 4; ni++) {
            int n_all = n0 + wid * 64 + ni * 16 + cl;   // w*512 + c
            int c = n_all & 511, w = n_all >> 9;
            float bk = b_kernel[c * 3 + w];
            #pragma unroll
            for (int r = 0; r < 4; r++) {
                int i_g = i0 + wid * 0 + mi * 16 + qd * 4 + r;
                int b = i_g >> 10, ii = i_g & 1023;
                G[((size_t)((b * 3 + w) * 1024 + ii)) * 512 + c] = f2bf(acc[mi][ni][r] + bk);
            }
        }
    }
}

// ---- Phase B (split-K x2): out[b,i,j] += sum_{w,c in K-half} G[b,w,i,c] * kp[b,j+w,c]
//      64i x 256j tiles, 4-wave blocks, grid 1024 (4 blocks/CU, 16 waves/CU),
//      XCD owns batch b; out pre-initialized with bias; f32 atomic accumulate ----
__global__ __launch_bounds__(256) void gemm_B(const unsigned short* __restrict__ G,
                                              const unsigned short* __restrict__ kp,
                                              float* __restrict__ out) {
    __shared__ unsigned short lds_a[3 * 64 * 32];   // [w][i][c]  12 KB
    __shared__ unsigned short lds_k[272 * 32];      // 17 chunks x 16 rows  17 KB
    int g = blockIdx.x;                 // 0..1023
    int b = g & 7, s = g >> 3;          // s 0..127
    int kh = s & 1;                     // K-half
    int j0 = ((s >> 1) & 3) * 256;
    int i0 = (s >> 3) * 64;             // 0..960
    int tid = threadIdx.x, wid = tid >> 6, lane = tid & 63;
    floatx4 acc[4][4] = {};
    const unsigned short* Gb  = G  + (size_t)b * 3 * 1024 * 512;
    const unsigned short* kpb = kp + (size_t)b * 1028 * 512;
    int k_beg = kh * 256;

    for (int kk = k_beg; kk < k_beg + 256; kk += 32) {
        // 29 staging chunks: 0..11 = A tiles, 12..28 = k-window rows (16 rows/chunk)
        #pragma unroll
        for (int s2 = 0; s2 < 8; ++s2) {
            int t = s2 * 4 + wid;       // 0..31, use t<29
            if (t < 29) {
                if (t < 12) {
                    int w = t >> 2, chunk = t & 3;
                    const unsigned short* ga = Gb + (size_t)(w * 1024 + i0 + chunk * 16 + (lane >> 2)) * 512
                                                  + kk + (lane & 3) * 8;
                    gl2lds16(ga, (char*)lds_a + t * 1024);
                } else {
                    int u = t - 12;     // 0..16, rows j0+u*16..+15 (rows >257 staged but unused)
                    const unsigned short* gk = kpb + (size_t)(j0 + u * 16 + (lane >> 2)) * 512
                                                   + kk + (lane & 3) * 8;
                    gl2lds16(gk, (char*)lds_k + u * 1024);
                }
            }
        }
        __syncthreads();
        int ra = lane & 15, q8 = (lane >> 4) * 8;
        #pragma unroll
        for (int w = 0; w < 3; ++w) {
            s8vec af[4], bfr[4];
            #pragma unroll
            for (int mi = 0; mi < 4; mi++)
                af[mi] = *(const s8vec*)(lds_a + (w * 64 + mi * 16 + ra) * 32 + q8);
            #pragma unroll
            for (int ni = 0; ni < 4; ni++) {
                int rr = wid * 64 + ni * 16 + ra + w;   // 0..257
                bfr[ni] = *(const s8vec*)(lds_k + rr * 32 + q8);
            }
            #pragma unroll
            for (int mi = 0; mi < 4; mi++)
                #pragma unroll
                for (int ni = 0; ni < 4; ni++)
                    acc[mi][ni] = __builtin_amdgcn_mfma_f32_16x16x32_bf16(af[mi], bfr[ni], acc[mi][ni], 0, 0, 0);
        }
        __syncthreads();
    }

    int cl = lane & 15, qd = lane >> 4;
    #pragma unroll
    for (int mi = 0; mi < 4; mi++) {
        #pragma unroll
        for (int r = 0; r < 4; r++) {
            int i_loc = mi * 16 + qd * 4 + r;
            float* orow = out + ((size_t)(b * 1024 + i0 + i_loc)) * 1024 + j0;
            #pragma unroll
            for (int ni = 0; ni < 4; ni++) {
                int j_loc = wid * 64 + ni * 16 + cl;
                unsafeAtomicAdd(&orow[j_loc], acc[mi][ni][r]);
            }
        }
    }
}

extern "C" void kernel_launch(void* const* d_in, const int* in_sizes, int n_in,
                              void* d_out, int out_size, void* d_ws, size_t ws_size,
                              hipStream_t stream) {
    const float* q        = (const float*)d_in[0];  // (8,1024,512)
    const float* k        = (const float*)d_in[1];  // (8,1024,512)
    const float* W_kernel = (const float*)d_in[2];  // (512,1536)
    const float* b_kernel = (const float*)d_in[3];  // (1536,)
    const float* W_bias   = (const float*)d_in[4];  // (512,1)
    const float* b_bias   = (const float*)d_in[5];  // (1,)
    const float* bias_b   = (const float*)d_in[6];  // (1,)
    float* out = (float*)d_out;                     // (8,1024,1024)

    // workspace carve (bytes): q_bf 8M | kp 8.03M+16K headroom | Wt 1.5M | G 24M | bias 32K
    char* ws = (char*)d_ws;
    unsigned short* q_bf = (unsigned short*)(ws);
    unsigned short* kp   = (unsigned short*)(ws + 8388608);
    unsigned short* Wt   = (unsigned short*)(ws + 8388608 + 8421376 + 16384);
    unsigned short* G    = (unsigned short*)(ws + 8388608 + 8421376 + 16384 + 1572864);
    float*          bsb  = (float*)(ws + 8388608 + 8421376 + 16384 + 1572864 + 25165824);

    cvt_all<<<6920, 256, 0, stream>>>(q, k, q_bf, kp, W_bias, b_bias, bsb, W_kernel, Wt);
    out_init<<<1024, 256, 0, stream>>>(bsb, bias_b, out);
    gemm_A<<<1536, 128, 0, stream>>>(q_bf, Wt, b_kernel, G);
    gemm_B<<<1024, 256, 0, stream>>>(G, kp, out);
}

// Round 8
// 162.412 us; speedup vs baseline: 1.2599x; 1.2599x over previous
//
#include <hip/hip_runtime.h>

// (B, Lq, Lk, D, C, KW) = (8, 1024, 1024, 512, 512, 3)

typedef __attribute__((ext_vector_type(8))) short s8vec;      // 8 x bf16 (4 VGPRs)
typedef __attribute__((ext_vector_type(16))) float floatx16;  // 32x32 MFMA accumulator

__device__ __forceinline__ unsigned short f2bf(float f) {
    union { float f; unsigned u; } v; v.f = f;
    unsigned r = (v.u + 0x7FFFu + ((v.u >> 16) & 1u)) >> 16;
    return (unsigned short)r;
}

__device__ __forceinline__ void gl2lds16(const void* g, void* l) {
    __builtin_amdgcn_global_load_lds(
        (__attribute__((address_space(1))) void*)(g),
        (__attribute__((address_space(3))) void*)(l), 16, 0, 0);
}

// ---- fused: q->bf16, k->padded bf16, zero pad, bias = q@W_bias+b_bias,
//      and W_kernel transpose -> Wt[w][c][d] bf16 ----
__global__ void cvt_all(const float* __restrict__ q, const float* __restrict__ k,
                        unsigned short* __restrict__ qbf, unsigned short* __restrict__ kp,
                        const float* __restrict__ Wb, const float* __restrict__ b_bias,
                        float* __restrict__ biasb,
                        const float* __restrict__ W, unsigned short* __restrict__ Wt) {
    int blk = blockIdx.x;
    if (blk < 4104) {
        int t = blk * 256 + threadIdx.x;
        if (t < 524288) {                       // q: 8*1024*512 / 8
            const float4* p = (const float4*)q + 2 * (size_t)t;
            float4 a = p[0], b = p[1];
            union { unsigned short s[8]; uint4 v; } o;
            o.s[0]=f2bf(a.x); o.s[1]=f2bf(a.y); o.s[2]=f2bf(a.z); o.s[3]=f2bf(a.w);
            o.s[4]=f2bf(b.x); o.s[5]=f2bf(b.y); o.s[6]=f2bf(b.z); o.s[7]=f2bf(b.w);
            ((uint4*)qbf)[t] = o.v;
        } else if (t < 1048576) {               // k -> padded kp
            int e8 = t - 524288;
            size_t e = (size_t)e8 * 8;
            int b = e8 >> 16;
            int j = (e8 >> 6) & 1023;
            int c = (e8 & 63) * 8;
            const float4* p = (const float4*)(k + e);
            float4 a = p[0], bb = p[1];
            union { unsigned short s[8]; uint4 v; } o;
            o.s[0]=f2bf(a.x); o.s[1]=f2bf(a.y); o.s[2]=f2bf(a.z); o.s[3]=f2bf(a.w);
            o.s[4]=f2bf(bb.x); o.s[5]=f2bf(bb.y); o.s[6]=f2bf(bb.z); o.s[7]=f2bf(bb.w);
            *(uint4*)(kp + ((size_t)(b * 1028 + j + 1) * 512 + c)) = o.v;
        } else if (t < 1050624) {               // zero pad rows
            int z = t - 1048576;
            int b = z >> 8, r = (z >> 6) & 3, ch = z & 63;
            int row = r ? (1024 + r) : 0;
            *(uint4*)(kp + ((size_t)(b * 1028 + row) * 512 + ch * 8)) = make_uint4(0u,0u,0u,0u);
        }
    } else if (blk < 6152) {                    // bias: one wave per row
        int row  = (blk - 4104) * 4 + (threadIdx.x >> 6);
        int lane = threadIdx.x & 63;
        const float4* qr = (const float4*)(q + (size_t)row * 512) + lane * 2;
        const float4* wb = (const float4*)Wb + lane * 2;
        float4 a0 = qr[0], a1 = qr[1], b0 = wb[0], b1 = wb[1];
        float s = a0.x*b0.x + a0.y*b0.y + a0.z*b0.z + a0.w*b0.w
                + a1.x*b1.x + a1.y*b1.y + a1.z*b1.z + a1.w*b1.w;
        #pragma unroll
        for (int off = 32; off > 0; off >>= 1) s += __shfl_down(s, off);
        if (lane == 0) biasb[row] = s + b_bias[0];
    } else {                                    // W transpose: 32x32 tile per block
        __shared__ float lds[32][33];
        int p = blk - 6152;                     // 0..767
        int cw0 = (p % 48) * 32, d0 = (p / 48) * 32;
        int tid = threadIdx.x;
        #pragma unroll
        for (int rep = 0; rep < 4; rep++) {
            int e = rep * 256 + tid, dy = e >> 5, dx = e & 31;
            lds[dy][dx] = W[(size_t)(d0 + dy) * 1536 + cw0 + dx];
        }
        __syncthreads();
        #pragma unroll
        for (int rep = 0; rep < 4; rep++) {
            int e = rep * 256 + tid, cy = e >> 5, cx = e & 31;
            int cw = cw0 + cy, c = cw / 3, w = cw % 3;
            Wt[((size_t)(w * 512 + c)) * 512 + d0 + cx] = f2bf(lds[cx][cy]);
        }
    }
}

// ---- Phase A: G[b][w][i][c] = bf16( q_bf(8192x512) @ Wt(1536x512)^T + b_kernel )
//      64m x 128n tiles, 2-wave blocks, 32x32x16 MFMA, grid 1536, XCD swizzle ----
__global__ __launch_bounds__(128) void gemm_A(const unsigned short* __restrict__ Abf,
                                              const unsigned short* __restrict__ Bbf,
                                              const float* __restrict__ b_kernel,
                                              unsigned short* __restrict__ G) {
    __shared__ unsigned short lds_a[64 * 32];    // 4 KB
    __shared__ unsigned short lds_b[128 * 32];   // 8 KB
    int g = blockIdx.x;                 // 0..1535
    int xcd = g & 7, slot = g >> 3;     // slot 0..191
    int i_blk = xcd * 16 + (slot & 15); // 0..127
    int n_blk = slot >> 4;              // 0..11
    int i0 = i_blk * 64, n0 = n_blk * 128;
    int tid = threadIdx.x, wid = tid >> 6, lane = tid & 63;
    floatx16 acc[2][2] = {};

    for (int kk = 0; kk < 512; kk += 32) {
        #pragma unroll
        for (int s = 0; s < 6; ++s) {
            int t = s * 2 + wid;        // 0..11; 16 rows x 64B per chunk
            if (t < 4) {
                const unsigned short* ga = Abf + (size_t)(i0 + t * 16 + (lane >> 2)) * 512 + kk + (lane & 3) * 8;
                gl2lds16(ga, (char*)lds_a + t * 1024);
            } else {
                int u = t - 4;
                const unsigned short* gb = Bbf + (size_t)(n0 + u * 16 + (lane >> 2)) * 512 + kk + (lane & 3) * 8;
                gl2lds16(gb, (char*)lds_b + u * 1024);
            }
        }
        __syncthreads();
        int rw = lane & 31, kq = (lane >> 5) * 8;   // A/B frag: [row=lane&31][k=(lane>>5)*8+j]
        s8vec af[2][2], bf_[2][2];
        #pragma unroll
        for (int mt = 0; mt < 2; mt++)
            #pragma unroll
            for (int kc = 0; kc < 2; kc++)
                af[mt][kc] = *(const s8vec*)(lds_a + (mt * 32 + rw) * 32 + kc * 16 + kq);
        #pragma unroll
        for (int nt = 0; nt < 2; nt++)
            #pragma unroll
            for (int kc = 0; kc < 2; kc++)
                bf_[nt][kc] = *(const s8vec*)(lds_b + (wid * 64 + nt * 32 + rw) * 32 + kc * 16 + kq);
        #pragma unroll
        for (int mt = 0; mt < 2; mt++)
            #pragma unroll
            for (int nt = 0; nt < 2; nt++)
                #pragma unroll
                for (int kc = 0; kc < 2; kc++)
                    acc[mt][nt] = __builtin_amdgcn_mfma_f32_32x32x16_bf16(af[mt][kc], bf_[nt][kc], acc[mt][nt], 0, 0, 0);
        __syncthreads();
    }

    // C/D: col=lane&31, row=(reg&3)+8*(reg>>2)+4*(lane>>5)
    int col = lane & 31, q4 = (lane >> 5) * 4;
    #pragma unroll
    for (int mt = 0; mt < 2; mt++) {
        #pragma unroll
        for (int nt = 0; nt < 2; nt++) {
            int n_all = n0 + wid * 64 + nt * 32 + col;   // w*512 + c
            int c = n_all & 511, w = n_all >> 9;
            float bk = b_kernel[c * 3 + w];
            #pragma unroll
            for (int reg = 0; reg < 16; reg++) {
                int i_g = i0 + mt * 32 + (reg & 3) + 8 * (reg >> 2) + q4;
                int b = i_g >> 10, ii = i_g & 1023;
                G[((size_t)((b * 3 + w) * 1024 + ii)) * 512 + c] = f2bf(acc[mt][nt][reg] + bk);
            }
        }
    }
}

// ---- Phase B: out[b,i,j] = sum_w sum_c G[b,w,i,c] * kp[b,j+w,c] + bias[b,i] + bias_b
//      64i x 128j tiles, 2-wave blocks, 32x32x16 MFMA, grid 1024, XCD owns batch b ----
__global__ __launch_bounds__(128) void gemm_B(const unsigned short* __restrict__ G,
                                              const unsigned short* __restrict__ kp,
                                              const float* __restrict__ biasb,
                                              const float* __restrict__ bias_b,
                                              float* __restrict__ out) {
    __shared__ unsigned short lds_a[3 * 64 * 32];   // [w][i][c]  12 KB
    __shared__ unsigned short lds_k[144 * 32];      // 9 chunks x 16 rows  9 KB
    int g = blockIdx.x;                 // 0..1023
    int b = g & 7, slot = g >> 3;       // slot 0..127
    int j0 = (slot & 7) * 128;
    int i0 = (slot >> 3) * 64;
    int tid = threadIdx.x, wid = tid >> 6, lane = tid & 63;
    floatx16 acc[2][2] = {};
    const unsigned short* Gb  = G  + (size_t)b * 3 * 1024 * 512;
    const unsigned short* kpb = kp + (size_t)b * 1028 * 512;
    float bb = bias_b[0];

    for (int kk = 0; kk < 512; kk += 32) {
        // 21 staging chunks: 0..11 = A (w = t>>2, sub = t&3), 12..20 = k rows
        #pragma unroll
        for (int s = 0; s < 11; ++s) {
            int t = s * 2 + wid;        // wave0: evens, wave1: odds
            if (t < 21) {
                if (t < 12) {
                    int w = t >> 2, chunk = t & 3;
                    const unsigned short* ga = Gb + (size_t)(w * 1024 + i0 + chunk * 16 + (lane >> 2)) * 512
                                                  + kk + (lane & 3) * 8;
                    gl2lds16(ga, (char*)lds_a + t * 1024);
                } else {
                    int u = t - 12;     // 0..8
                    const unsigned short* gk = kpb + (size_t)(j0 + u * 16 + (lane >> 2)) * 512
                                                   + kk + (lane & 3) * 8;
                    gl2lds16(gk, (char*)lds_k + u * 1024);
                }
            }
        }
        __syncthreads();
        int rw = lane & 31, kq = (lane >> 5) * 8;
        #pragma unroll
        for (int w = 0; w < 3; ++w) {
            s8vec af[2][2], bfr[2][2];
            #pragma unroll
            for (int mt = 0; mt < 2; mt++)
                #pragma unroll
                for (int kc = 0; kc < 2; kc++)
                    af[mt][kc] = *(const s8vec*)(lds_a + (w * 64 + mt * 32 + rw) * 32 + kc * 16 + kq);
            #pragma unroll
            for (int nt = 0; nt < 2; nt++) {
                int rr = wid * 64 + nt * 32 + rw + w;   // shifted k-window row, 0..129
                #pragma unroll
                for (int kc = 0; kc < 2; kc++)
                    bfr[nt][kc] = *(const s8vec*)(lds_k + rr * 32 + kc * 16 + kq);
            }
            #pragma unroll
            for (int mt = 0; mt < 2; mt++)
                #pragma unroll
                for (int nt = 0; nt < 2; nt++)
                    #pragma unroll
                    for (int kc = 0; kc < 2; kc++)
                        acc[mt][nt] = __builtin_amdgcn_mfma_f32_32x32x16_bf16(af[mt][kc], bfr[nt][kc], acc[mt][nt], 0, 0, 0);
        }
        __syncthreads();
    }

    int col = lane & 31, q4 = (lane >> 5) * 4;
    #pragma unroll
    for (int mt = 0; mt < 2; mt++) {
        #pragma unroll
        for (int reg = 0; reg < 16; reg++) {
            int i_loc = mt * 32 + (reg & 3) + 8 * (reg >> 2) + q4;
            float bv = biasb[b * 1024 + i0 + i_loc] + bb;
            #pragma unroll
            for (int nt = 0; nt < 2; nt++) {
                int j_loc = wid * 64 + nt * 32 + col;
                out[((size_t)(b * 1024 + i0 + i_loc)) * 1024 + j0 + j_loc] = acc[mt][nt][reg] + bv;
            }
        }
    }
}

extern "C" void kernel_launch(void* const* d_in, const int* in_sizes, int n_in,
                              void* d_out, int out_size, void* d_ws, size_t ws_size,
                              hipStream_t stream) {
    const float* q        = (const float*)d_in[0];  // (8,1024,512)
    const float* k        = (const float*)d_in[1];  // (8,1024,512)
    const float* W_kernel = (const float*)d_in[2];  // (512,1536)
    const float* b_kernel = (const float*)d_in[3];  // (1536,)
    const float* W_bias   = (const float*)d_in[4];  // (512,1)
    const float* b_bias   = (const float*)d_in[5];  // (1,)
    const float* bias_b   = (const float*)d_in[6];  // (1,)
    float* out = (float*)d_out;                     // (8,1024,1024)

    // workspace carve (bytes): q_bf 8M | kp 8.03M+16K headroom | Wt 1.5M | G 24M | bias 32K
    char* ws = (char*)d_ws;
    unsigned short* q_bf = (unsigned short*)(ws);
    unsigned short* kp   = (unsigned short*)(ws + 8388608);
    unsigned short* Wt   = (unsigned short*)(ws + 8388608 + 8421376 + 16384);
    unsigned short* G    = (unsigned short*)(ws + 8388608 + 8421376 + 16384 + 1572864);
    float*          bsb  = (float*)(ws + 8388608 + 8421376 + 16384 + 1572864 + 25165824);

    cvt_all<<<6920, 256, 0, stream>>>(q, k, q_bf, kp, W_bias, b_bias, bsb, W_kernel, Wt);
    gemm_A<<<1536, 128, 0, stream>>>(q_bf, Wt, b_kernel, G);
    gemm_B<<<1024, 128, 0, stream>>>(G, kp, bsb, bias_b, out);
}

// Round 9
// 142.512 us; speedup vs baseline: 1.4359x; 1.1396x over previous
//
#include <hip/hip_runtime.h>

// (B, Lq, Lk, D, C, KW) = (8, 1024, 1024, 512, 512, 3)

typedef __attribute__((ext_vector_type(8))) short s8vec;    // 8 x bf16 (4 VGPRs)
typedef __attribute__((ext_vector_type(4))) float floatx4;  // MFMA accumulator

__device__ __forceinline__ unsigned short f2bf(float f) {
    union { float f; unsigned u; } v; v.f = f;
    unsigned r = (v.u + 0x7FFFu + ((v.u >> 16) & 1u)) >> 16;
    return (unsigned short)r;
}

__device__ __forceinline__ void gl2lds16(const void* g, void* l) {
    __builtin_amdgcn_global_load_lds(
        (__attribute__((address_space(1))) void*)(g),
        (__attribute__((address_space(3))) void*)(l), 16, 0, 0);
}

// ---- fused: q->bf16, k->padded bf16, zero pad, bias = q@W_bias+b_bias,
//      and W_kernel transpose -> Wt[w][c][d] bf16 ----
__global__ void cvt_all(const float* __restrict__ q, const float* __restrict__ k,
                        unsigned short* __restrict__ qbf, unsigned short* __restrict__ kp,
                        const float* __restrict__ Wb, const float* __restrict__ b_bias,
                        float* __restrict__ biasb,
                        const float* __restrict__ W, unsigned short* __restrict__ Wt) {
    int blk = blockIdx.x;
    if (blk < 4104) {
        int t = blk * 256 + threadIdx.x;
        if (t < 524288) {                       // q: 8*1024*512 / 8
            const float4* p = (const float4*)q + 2 * (size_t)t;
            float4 a = p[0], b = p[1];
            union { unsigned short s[8]; uint4 v; } o;
            o.s[0]=f2bf(a.x); o.s[1]=f2bf(a.y); o.s[2]=f2bf(a.z); o.s[3]=f2bf(a.w);
            o.s[4]=f2bf(b.x); o.s[5]=f2bf(b.y); o.s[6]=f2bf(b.z); o.s[7]=f2bf(b.w);
            ((uint4*)qbf)[t] = o.v;
        } else if (t < 1048576) {               // k -> padded kp
            int e8 = t - 524288;
            size_t e = (size_t)e8 * 8;
            int b = e8 >> 16;
            int j = (e8 >> 6) & 1023;
            int c = (e8 & 63) * 8;
            const float4* p = (const float4*)(k + e);
            float4 a = p[0], bb = p[1];
            union { unsigned short s[8]; uint4 v; } o;
            o.s[0]=f2bf(a.x); o.s[1]=f2bf(a.y); o.s[2]=f2bf(a.z); o.s[3]=f2bf(a.w);
            o.s[4]=f2bf(bb.x); o.s[5]=f2bf(bb.y); o.s[6]=f2bf(bb.z); o.s[7]=f2bf(bb.w);
            *(uint4*)(kp + ((size_t)(b * 1028 + j + 1) * 512 + c)) = o.v;
        } else if (t < 1050624) {               // zero pad rows
            int z = t - 1048576;
            int b = z >> 8, r = (z >> 6) & 3, ch = z & 63;
            int row = r ? (1024 + r) : 0;
            *(uint4*)(kp + ((size_t)(b * 1028 + row) * 512 + ch * 8)) = make_uint4(0u,0u,0u,0u);
        }
    } else if (blk < 6152) {                    // bias: one wave per row
        int row  = (blk - 4104) * 4 + (threadIdx.x >> 6);
        int lane = threadIdx.x & 63;
        const float4* qr = (const float4*)(q + (size_t)row * 512) + lane * 2;
        const float4* wb = (const float4*)Wb + lane * 2;
        float4 a0 = qr[0], a1 = qr[1], b0 = wb[0], b1 = wb[1];
        float s = a0.x*b0.x + a0.y*b0.y + a0.z*b0.z + a0.w*b0.w
                + a1.x*b1.x + a1.y*b1.y + a1.z*b1.z + a1.w*b1.w;
        #pragma unroll
        for (int off = 32; off > 0; off >>= 1) s += __shfl_down(s, off);
        if (lane == 0) biasb[row] = s + b_bias[0];
    } else {                                    // W transpose: 32x32 tile per block
        __shared__ float lds[32][33];
        int p = blk - 6152;                     // 0..767
        int cw0 = (p % 48) * 32, d0 = (p / 48) * 32;
        int tid = threadIdx.x;
        #pragma unroll
        for (int rep = 0; rep < 4; rep++) {
            int e = rep * 256 + tid, dy = e >> 5, dx = e & 31;
            lds[dy][dx] = W[(size_t)(d0 + dy) * 1536 + cw0 + dx];
        }
        __syncthreads();
        #pragma unroll
        for (int rep = 0; rep < 4; rep++) {
            int e = rep * 256 + tid, cy = e >> 5, cx = e & 31;
            int cw = cw0 + cy, c = cw / 3, w = cw % 3;
            Wt[((size_t)(w * 512 + c)) * 512 + d0 + cx] = f2bf(lds[cx][cy]);
        }
    }
}

// ---- Phase A: G[b][w][i][c] = bf16( q_bf(8192x512) @ Wt(1536x512)^T + b_kernel )
//      128m x 128n tiles (m97 shape), 4-wave blocks, grid 768, XCD swizzle ----
__global__ __launch_bounds__(256) void gemm_A(const unsigned short* __restrict__ Abf,
                                              const unsigned short* __restrict__ Bbf,
                                              const float* __restrict__ b_kernel,
                                              unsigned short* __restrict__ G) {
    __shared__ unsigned short lds_a[128 * 32];
    __shared__ unsigned short lds_b[128 * 32];
    int g = blockIdx.x;                 // 0..767
    int xcd = g & 7, slot = g >> 3;     // slot 0..95
    int n_blk = slot / 8;               // 0..11
    int i_blk = xcd * 8 + (slot & 7);   // 0..63 (1 MB q-slice per XCD)
    int i0 = i_blk * 128;
    int n0 = n_blk * 128;
    int tid = threadIdx.x, wid = tid >> 6, lane = tid & 63;
    int wm = wid >> 1, wn = wid & 1;
    floatx4 acc[4][4] = {};

    for (int kk = 0; kk < 512; kk += 32) {
        #pragma unroll
        for (int s = 0; s < 2; ++s) {
            int t = wid * 2 + s;   // 0..7, wave-uniform, 16 rows per inst
            const unsigned short* ga = Abf + (size_t)(i0 + t * 16 + (lane >> 2)) * 512 + kk + (lane & 3) * 8;
            gl2lds16(ga, (char*)lds_a + t * 1024);
            const unsigned short* gb = Bbf + (size_t)(n0 + t * 16 + (lane >> 2)) * 512 + kk + (lane & 3) * 8;
            gl2lds16(gb, (char*)lds_b + t * 1024);
        }
        __syncthreads();
        int ra = lane & 15, q8 = (lane >> 4) * 8;
        s8vec af[4], bf_[4];
        #pragma unroll
        for (int mi = 0; mi < 4; mi++)
            af[mi] = *(const s8vec*)(lds_a + (wm * 64 + mi * 16 + ra) * 32 + q8);
        #pragma unroll
        for (int ni = 0; ni < 4; ni++)
            bf_[ni] = *(const s8vec*)(lds_b + (wn * 64 + ni * 16 + ra) * 32 + q8);
        #pragma unroll
        for (int mi = 0; mi < 4; mi++)
            #pragma unroll
            for (int ni = 0; ni < 4; ni++)
                acc[mi][ni] = __builtin_amdgcn_mfma_f32_16x16x32_bf16(af[mi], bf_[ni], acc[mi][ni], 0, 0, 0);
        __syncthreads();
    }

    int cl = lane & 15, qd = lane >> 4;
    #pragma unroll
    for (int mi = 0; mi < 4; mi++) {
        #pragma unroll
        for (int ni = 0; ni < 4; ni++) {
            int n_all = n0 + wn * 64 + ni * 16 + cl;   // w*512 + c
            int c = n_all & 511, w = n_all >> 9;
            float bk = b_kernel[c * 3 + w];
            #pragma unroll
            for (int r = 0; r < 4; r++) {
                int i_g = i0 + wm * 64 + mi * 16 + qd * 4 + r;
                int b = i_g >> 10, ii = i_g & 1023;
                G[((size_t)((b * 3 + w) * 1024 + ii)) * 512 + c] = f2bf(acc[mi][ni][r] + bk);
            }
        }
    }
}

// ---- Phase B: out[b,i,j] = sum_w sum_c G[b,w,i,c] * kp[b,j+w,c] + bias[b,i] + bias_b
//      64i x 256j tiles, 4 waves along j (64x64 wave-tile), grid 512,
//      XCD owns batch b (G[b] 3MB + kp[b] 1MB resident in its L2) ----
__global__ __launch_bounds__(256) void gemm_B(const unsigned short* __restrict__ G,
                                              const unsigned short* __restrict__ kp,
                                              const float* __restrict__ biasb,
                                              const float* __restrict__ bias_b,
                                              float* __restrict__ out) {
    __shared__ unsigned short lds_a[3 * 64 * 32];   // [w][i][c]  12 KB
    __shared__ unsigned short lds_k[272 * 32];      // 17 chunks x 16 rows  17 KB
    int g = blockIdx.x;                 // 0..511
    int b = g & 7, slot = g >> 3;       // slot 0..63
    int j0 = (slot & 3) * 256;
    int i0 = (slot >> 2) * 64;          // 0..960
    int tid = threadIdx.x, wid = tid >> 6, lane = tid & 63;
    floatx4 acc[4][4] = {};
    const unsigned short* Gb  = G  + (size_t)b * 3 * 1024 * 512;
    const unsigned short* kpb = kp + (size_t)b * 1028 * 512;
    float bb = bias_b[0];

    for (int kk = 0; kk < 512; kk += 32) {
        // 29 staging chunks: 0..11 = A tiles (w = t>>2, sub = t&3), 12..28 = k rows
        #pragma unroll
        for (int s2 = 0; s2 < 8; ++s2) {
            int t = s2 * 4 + wid;       // 0..31, use t<29
            if (t < 29) {
                if (t < 12) {
                    int w = t >> 2, chunk = t & 3;
                    const unsigned short* ga = Gb + (size_t)(w * 1024 + i0 + chunk * 16 + (lane >> 2)) * 512
                                                  + kk + (lane & 3) * 8;
                    gl2lds16(ga, (char*)lds_a + t * 1024);
                } else {
                    int u = t - 12;     // 0..16, rows j0+u*16 .. +15 (max row 1039: 11-row
                                        // over-read for b=7 lands in the 16K headroom)
                    const unsigned short* gk = kpb + (size_t)(j0 + u * 16 + (lane >> 2)) * 512
                                                   + kk + (lane & 3) * 8;
                    gl2lds16(gk, (char*)lds_k + u * 1024);
                }
            }
        }
        __syncthreads();
        int ra = lane & 15, q8 = (lane >> 4) * 8;
        #pragma unroll
        for (int w = 0; w < 3; ++w) {
            s8vec af[4], bfr[4];
            #pragma unroll
            for (int mi = 0; mi < 4; mi++)
                af[mi] = *(const s8vec*)(lds_a + (w * 64 + mi * 16 + ra) * 32 + q8);
            #pragma unroll
            for (int ni = 0; ni < 4; ni++) {
                int rr = wid * 64 + ni * 16 + ra + w;   // 0..257
                bfr[ni] = *(const s8vec*)(lds_k + rr * 32 + q8);
            }
            #pragma unroll
            for (int mi = 0; mi < 4; mi++)
                #pragma unroll
                for (int ni = 0; ni < 4; ni++)
                    acc[mi][ni] = __builtin_amdgcn_mfma_f32_16x16x32_bf16(af[mi], bfr[ni], acc[mi][ni], 0, 0, 0);
        }
        __syncthreads();
    }

    int cl = lane & 15, qd = lane >> 4;
    #pragma unroll
    for (int mi = 0; mi < 4; mi++) {
        #pragma unroll
        for (int r = 0; r < 4; r++) {
            int i_loc = mi * 16 + qd * 4 + r;
            float bv = biasb[b * 1024 + i0 + i_loc] + bb;
            float* orow = out + ((size_t)(b * 1024 + i0 + i_loc)) * 1024 + j0;
            #pragma unroll
            for (int ni = 0; ni < 4; ni++) {
                int j_loc = wid * 64 + ni * 16 + cl;
                orow[j_loc] = acc[mi][ni][r] + bv;
            }
        }
    }
}

extern "C" void kernel_launch(void* const* d_in, const int* in_sizes, int n_in,
                              void* d_out, int out_size, void* d_ws, size_t ws_size,
                              hipStream_t stream) {
    const float* q        = (const float*)d_in[0];  // (8,1024,512)
    const float* k        = (const float*)d_in[1];  // (8,1024,512)
    const float* W_kernel = (const float*)d_in[2];  // (512,1536)
    const float* b_kernel = (const float*)d_in[3];  // (1536,)
    const float* W_bias   = (const float*)d_in[4];  // (512,1)
    const float* b_bias   = (const float*)d_in[5];  // (1,)
    const float* bias_b   = (const float*)d_in[6];  // (1,)
    float* out = (float*)d_out;                     // (8,1024,1024)

    // workspace carve (bytes): q_bf 8M | kp 8.03M+16K headroom | Wt 1.5M | G 24M | bias 32K
    char* ws = (char*)d_ws;
    unsigned short* q_bf = (unsigned short*)(ws);
    unsigned short* kp   = (unsigned short*)(ws + 8388608);
    unsigned short* Wt   = (unsigned short*)(ws + 8388608 + 8421376 + 16384);
    unsigned short* G    = (unsigned short*)(ws + 8388608 + 8421376 + 16384 + 1572864);
    float*          bsb  = (float*)(ws + 8388608 + 8421376 + 16384 + 1572864 + 25165824);

    cvt_all<<<6920, 256, 0, stream>>>(q, k, q_bf, kp, W_bias, b_bias, bsb, W_kernel, Wt);
    gemm_A<<<768, 256, 0, stream>>>(q_bf, Wt, b_kernel, G);
    gemm_B<<<512, 256, 0, stream>>>(G, kp, bsb, bias_b, out);
}